// Round 1
// baseline (234.855 us; speedup 1.0000x reference)
//
#include <hip/hip_runtime.h>
#include <math.h>

// Phase quantizer, v2 (STEPS=2), f32 in/out.
// R2: (a) 5 dispatches -> 3: the two 1-block reduce kernels are replaced by a
//     redundant per-block reduction of the 4096 partials at the top of K2/K3
//     (48 KB broadcast read, L2-cached; removes 2 dispatch serializations);
//     (b) serpentine traversal: K2 walks its grid-stride windows in REVERSE
//     order so it starts on the lines K1 touched last (256 MB input == 256 MB
//     Infinity Cache -> forward re-read is the LRU worst case, reverse re-read
//     hits); K3 walks forward again (K2 ended at low addresses).
//     Per-element numerics identical to R1.

#define NM_PI     3.14159265358979323846f
#define NM_PI2_4  2.46740110027233965468f   // (pi/2)^2
#define NM_PISQ   9.86960440108935861883f   // pi^2

#define NBLK 4096
#define TPB  256

// atan(r) for r in [0,1], A&S 4.4.49, |err| <= 1e-5 rad.
__device__ __forceinline__ float atan_poly(float r) {
  float r2 = r * r;
  float q = 0.0208351f;
  q = fmaf(q, r2, -0.0851330f);
  q = fmaf(q, r2, 0.1801410f);
  q = fmaf(q, r2, -0.3302995f);
  q = fmaf(q, r2, 0.9998660f);
  return r * q;
}

// Soft assignment directions (softmax over 4 phase centers), branchless.
// k_t = pi/tau, c1 = exp(-(pi/2)^2/tau), c2 = exp(-pi^2/tau).
__device__ __forceinline__ void soft_dirs(float x, float y, float k_t,
                                          float c1, float c2,
                                          float& dre, float& dim) {
  float ax = fabsf(x), ay = fabsf(y);
  float hi = fmaxf(ax, ay), lo = fminf(ax, ay);
  float r = lo * __builtin_amdgcn_rcpf(fmaxf(hi, 1e-30f));
  float u = atan_poly(r);                    // angle from dominant axis
  float P = __expf(k_t * u);
  float Pi = __builtin_amdgcn_rcpf(P);
  float wo = c2 * P * P;                     // opposite axis
  float wp = c1 * P;                         // near perpendicular (minor sign)
  float wq = c1 * Pi;                        // far perpendicular
  float inv_sum = __builtin_amdgcn_rcpf(1.0f + wo + wp + wq);
  float dmaj = (1.0f - wo) * inv_sum;
  float dmin = (wp - wq) * inv_sum;
  bool xdom = (ax >= ay);
  float sx = copysignf(1.0f, x), sy = copysignf(1.0f, y);
  dre = sx * (xdom ? dmaj : dmin);
  dim = sy * (xdom ? dmin : dmaj);
}

__device__ __forceinline__ float finalize_s(float sum, unsigned cnt) {
  float c = (float)(cnt > 0u ? cnt : 1u);
  float s = sum * __builtin_amdgcn_rcpf(c);
  s = (cnt > 0u) ? s : 0.0f;
  return fmaxf(s, 1e-6f);
}

// In-block all-reduce (TPB=256 -> 4 waves); result valid in ALL threads.
__device__ __forceinline__ void block_allreduce3(float& sre, float& sim,
                                                 unsigned& cnt) {
  #pragma unroll
  for (int o = 32; o > 0; o >>= 1) {
    sre += __shfl_down(sre, o);
    sim += __shfl_down(sim, o);
    cnt += __shfl_down(cnt, o);
  }
  __shared__ float rf0[4];
  __shared__ float rf1[4];
  __shared__ unsigned ru[4];
  int wave = threadIdx.x >> 6;
  int lane = threadIdx.x & 63;
  if (lane == 0) { rf0[wave] = sre; rf1[wave] = sim; ru[wave] = cnt; }
  __syncthreads();
  sre = rf0[0] + rf0[1] + rf0[2] + rf0[3];
  sim = rf1[0] + rf1[1] + rf1[2] + rf1[3];
  cnt = ru[0] + ru[1] + ru[2] + ru[3];
  __syncthreads();   // allow safe LDS reuse on a second call
}

// Redundant per-block reduction of NBLK partials -> finalized scales (all
// threads get the same values). 48 KB, same addresses for every block -> L2
// broadcast; replaces the 1-block pq_reduce dispatch.
__device__ __forceinline__ void reduce_partials(const float* __restrict__ psre,
                                                const float* __restrict__ psim,
                                                const unsigned* __restrict__ pcnt,
                                                unsigned nm,
                                                float& s_re, float& s_im) {
  float a = 0.f, b = 0.f;
  unsigned c = 0u;
  for (int i = threadIdx.x; i < NBLK; i += TPB) {   // 16 iters
    a += psre[i];
    b += psim[i];
    c += pcnt[i];
  }
  block_allreduce3(a, b, c);
  s_re = finalize_s(a, c);
  s_im = finalize_s(b, nm - c);
}

// K1: step-1 scale partials. mask_real == (|y| <= |x|); no transcendentals.
// Forward traversal (cold read).
__global__ __launch_bounds__(TPB) void pq_k1(const float4* __restrict__ wr,
                                             const float4* __restrict__ wi,
                                             int n4, float* __restrict__ psre,
                                             float* __restrict__ psim,
                                             unsigned* __restrict__ pcnt) {
  float sre = 0.f, sim = 0.f;
  unsigned cnt = 0u;
  int stride = gridDim.x * blockDim.x;
  for (int i = blockIdx.x * blockDim.x + threadIdx.x; i < n4; i += stride) {
    float4 r = wr[i], g = wi[i];
    float xs[4] = {r.x, r.y, r.z, r.w};
    float ys[4] = {g.x, g.y, g.z, g.w};
    #pragma unroll
    for (int k = 0; k < 4; ++k) {
      float ax = fabsf(xs[k]), ay = fabsf(ys[k]);
      bool is_re = (ay <= ax);
      sre += is_re ? ax : 0.f;
      sim += is_re ? 0.f : ay;
      cnt += is_re ? 1u : 0u;
    }
  }
  block_allreduce3(sre, sim, cnt);
  if (threadIdx.x == 0) {
    psre[blockIdx.x] = sre;
    psim[blockIdx.x] = sim;
    pcnt[blockIdx.x] = cnt;
  }
}

// K2: inline-reduce pass-1 partials, recompute step 1, accumulate step-2
// scale partials. REVERSE window order (serpentine vs K1).
__global__ __launch_bounds__(TPB) void pq_k2(const float4* __restrict__ wr,
                                             const float4* __restrict__ wi,
                                             int n4,
                                             const float* __restrict__ temp,
                                             const float* __restrict__ p1sre,
                                             const float* __restrict__ p1sim,
                                             const unsigned* __restrict__ p1cnt,
                                             unsigned nm,
                                             float* __restrict__ psre,
                                             float* __restrict__ psim,
                                             unsigned* __restrict__ pcnt) {
  float s_re1, s_im1;
  reduce_partials(p1sre, p1sim, p1cnt, nm, s_re1, s_im1);

  float it = __builtin_amdgcn_rcpf(temp[0] + 1e-6f);
  float k_t = NM_PI * it;
  float c1 = __expf(-NM_PI2_4 * it);
  float c2 = __expf(-NM_PISQ * it);
  float sre = 0.f, sim = 0.f;
  unsigned cnt = 0u;
  int stride = gridDim.x * blockDim.x;
  int tid0 = blockIdx.x * blockDim.x + threadIdx.x;
  int last_base = ((n4 - 1) / stride) * stride;
  for (int base = last_base; base >= 0; base -= stride) {
    int i = tid0 + base;
    if (i < n4) {
      float4 r = wr[i], g = wi[i];
      float xs[4] = {r.x, r.y, r.z, r.w};
      float ys[4] = {g.x, g.y, g.z, g.w};
      #pragma unroll
      for (int k = 0; k < 4; ++k) {
        float x = xs[k], y = ys[k];
        float dre, dim;
        soft_dirs(x, y, k_t, c1, c2, dre, dim);
        float er = x - dre * s_re1;
        float ei = y - dim * s_im1;
        float ax = fabsf(er), ay = fabsf(ei);
        bool is_re = (ay <= ax);
        sre += is_re ? ax : 0.f;
        sim += is_re ? 0.f : ay;
        cnt += is_re ? 1u : 0u;
      }
    }
  }
  block_allreduce3(sre, sim, cnt);
  if (threadIdx.x == 0) {
    psre[blockIdx.x] = sre;
    psim[blockIdx.x] = sim;
    pcnt[blockIdx.x] = cnt;
  }
}

// K3: inline-reduce both partial sets, recompute steps 1+2, write outputs.
// Forward traversal (serpentine vs K2).
__global__ __launch_bounds__(TPB) void pq_k3(const float4* __restrict__ wr,
                                             const float4* __restrict__ wi,
                                             int n4,
                                             const float* __restrict__ temp,
                                             const float* __restrict__ p1sre,
                                             const float* __restrict__ p1sim,
                                             const unsigned* __restrict__ p1cnt,
                                             const float* __restrict__ p2sre,
                                             const float* __restrict__ p2sim,
                                             const unsigned* __restrict__ p2cnt,
                                             unsigned nm,
                                             float4* __restrict__ out) {
  float s_re1, s_im1, s_re2, s_im2;
  reduce_partials(p1sre, p1sim, p1cnt, nm, s_re1, s_im1);
  reduce_partials(p2sre, p2sim, p2cnt, nm, s_re2, s_im2);

  float it = __builtin_amdgcn_rcpf(temp[0] + 1e-6f);
  float k_t = NM_PI * it;
  float c1 = __expf(-NM_PI2_4 * it);
  float c2 = __expf(-NM_PISQ * it);
  int stride = gridDim.x * blockDim.x;
  for (int i = blockIdx.x * blockDim.x + threadIdx.x; i < n4; i += stride) {
    float4 r = wr[i], g = wi[i];
    float xs[4] = {r.x, r.y, r.z, r.w};
    float ys[4] = {g.x, g.y, g.z, g.w};
    float qr[4], qi[4];
    #pragma unroll
    for (int k = 0; k < 4; ++k) {
      float x = xs[k], y = ys[k];
      float d1re, d1im;
      soft_dirs(x, y, k_t, c1, c2, d1re, d1im);
      float q1r = d1re * s_re1;
      float q1i = d1im * s_im1;
      float er = x - q1r;
      float ei = y - q1i;
      float d2re, d2im;
      soft_dirs(er, ei, k_t, c1, c2, d2re, d2im);
      qr[k] = fmaf(d2re, s_re2, q1r);
      qi[k] = fmaf(d2im, s_im2, q1i);
    }
    float4 o0 = {qr[0], qr[1], qr[2], qr[3]};
    float4 o1 = {qi[0], qi[1], qi[2], qi[3]};
    out[i] = o0;
    out[n4 + i] = o1;
  }
}

extern "C" void kernel_launch(void* const* d_in, const int* in_sizes, int n_in,
                              void* d_out, int out_size, void* d_ws, size_t ws_size,
                              hipStream_t stream) {
  const float4* wr = (const float4*)d_in[0];
  const float4* wi = (const float4*)d_in[1];
  const float* temp = (const float*)d_in[2];
  int nm = in_sizes[0];
  int n4 = nm / 4;

  // ws layout (4B words):
  //   [8        .. 8+NB)     p1_sre
  //   [8+NB     .. 8+2NB)    p1_sim
  //   [8+2NB    .. 8+3NB)    p1_cnt (uint)
  //   [8+3NB    .. 8+6NB)    pass-2 partials, same order
  float* w32 = (float*)d_ws;
  unsigned* u32 = (unsigned*)d_ws;
  float* p1_sre = w32 + 8;
  float* p1_sim = p1_sre + NBLK;
  unsigned* p1_cnt = u32 + 8 + 2 * NBLK;
  float* p2_sre = w32 + 8 + 3 * NBLK;
  float* p2_sim = p2_sre + NBLK;
  unsigned* p2_cnt = u32 + 8 + 5 * NBLK;

  dim3 block(TPB);
  dim3 grid(NBLK);
  pq_k1<<<grid, block, 0, stream>>>(wr, wi, n4, p1_sre, p1_sim, p1_cnt);
  pq_k2<<<grid, block, 0, stream>>>(wr, wi, n4, temp,
                                    p1_sre, p1_sim, p1_cnt, (unsigned)nm,
                                    p2_sre, p2_sim, p2_cnt);
  pq_k3<<<grid, block, 0, stream>>>(wr, wi, n4, temp,
                                    p1_sre, p1_sim, p1_cnt,
                                    p2_sre, p2_sim, p2_cnt, (unsigned)nm,
                                    (float4*)d_out);
}